// Round 5
// baseline (2010.146 us; speedup 1.0000x reference)
//
#include <hip/hip_runtime.h>
#include <stdint.h>

#define N_SEQ 16384
#define T_LEN 16
#define E_DIM 256
#define H_DIM 256
#define B_SAMP 128
#define V_SIZE 10000

typedef __bf16 bf16x8 __attribute__((ext_vector_type(8)));
typedef float  f32x4  __attribute__((ext_vector_type(4)));
typedef unsigned short u16x8 __attribute__((ext_vector_type(8)));
typedef unsigned short ush;

__device__ __forceinline__ ush f2bf(float x) {
  unsigned int u = __float_as_uint(x);
  u = (u + 0x7fffu + ((u >> 16) & 1u)) >> 16;
  return (ush)u;
}
__device__ __forceinline__ float bf2f(ush v) {
  return __uint_as_float(((unsigned int)v) << 16);
}
__device__ __forceinline__ float sigmoidf_(float x) {
  return 1.0f / (1.0f + __expf(-x));
}
__device__ __forceinline__ float tanhf_(float x) {
  float e = __expf(2.0f * x);
  return 1.0f - 2.0f / (e + 1.0f);
}

// ---------------- prep kernels ----------------

__global__ __launch_bounds__(256) void k_lens(const int* __restrict__ tok, int* __restrict__ lens) {
  int n = blockIdx.x * 256 + threadIdx.x;
  const int* r = tok + n * T_LEN;
  int c = 0;
#pragma unroll
  for (int t = 0; t < T_LEN; ++t) c += (r[t] != 0);
  lens[n] = c;
}

__global__ __launch_bounds__(256) void k_hist(const int* __restrict__ lens, int* __restrict__ hist) {
  __shared__ int lh[17];
  if (threadIdx.x < 17) lh[threadIdx.x] = 0;
  __syncthreads();
  atomicAdd(&lh[lens[blockIdx.x * 256 + threadIdx.x]], 1);
  __syncthreads();
  if (threadIdx.x < 17) atomicAdd(&hist[threadIdx.x], lh[threadIdx.x]);
}

__global__ void k_offsets(const int* __restrict__ hist, int* __restrict__ cursor, int* __restrict__ cnts) {
  if (threadIdx.x == 0) {
    int off = 0;
    for (int l = 16; l >= 0; --l) { cursor[l] = off; off += hist[l]; }
    for (int t = 0; t < 16; ++t) {
      int c = 0;
      for (int l = t; l <= 16; ++l) c += hist[l];
      cnts[t] = c;
    }
  }
}

__global__ __launch_bounds__(256) void k_scatter(const int* __restrict__ tok, const int* __restrict__ lens,
                                                 int* __restrict__ cursor,
                                                 int* __restrict__ pinv, int* __restrict__ plens,
                                                 int* __restrict__ tokperm) {
  int n = blockIdx.x * 256 + threadIdx.x;
  int l = lens[n];
  int pos = atomicAdd(&cursor[l], 1);
  pinv[n] = pos;
  plens[pos] = l;
#pragma unroll
  for (int t = 0; t < T_LEN; ++t) tokperm[t * N_SEQ + pos] = tok[n * T_LEN + t];
}

__global__ __launch_bounds__(256) void k_embcvt(const float* __restrict__ emb, ush* __restrict__ out) {
  int i = blockIdx.x * 256 + threadIdx.x;
  out[i] = f2bf(emb[i]);
}

// Permuted weights: wpt[p][k], p = hb*64 + q*16 + jj  <->  gate-row r = q*256 + hb*16 + jj;
// k<256 -> W_ih[r][k], else W_hh[r][k-256].
__global__ __launch_bounds__(256) void k_wprep(const float* __restrict__ Wih_f, const float* __restrict__ Whh_f,
                                               const float* __restrict__ Wih_b, const float* __restrict__ Whh_b,
                                               ush* __restrict__ wpt_f, ush* __restrict__ wpt_b) {
  int id = blockIdx.x * 256 + threadIdx.x;  // < 2*1024*512
  int dir = id >> 19;
  int rem = id & ((1 << 19) - 1);
  int p = rem >> 9;
  int k = rem & 511;
  int hb = p >> 6, q = (p >> 4) & 3, jj = p & 15;
  int r = q * 256 + hb * 16 + jj;
  const float* Wih = dir ? Wih_b : Wih_f;
  const float* Whh = dir ? Whh_b : Whh_f;
  float v = (k < 256) ? Wih[r * 256 + k] : Whh[r * 256 + (k - 256)];
  ush* o = dir ? wpt_b : wpt_f;
  o[p * 512 + k] = f2bf(v);
}

// ---------------- LSTM step: barrier-free, LDS-free per-wave GEMM ----------------
// Each wave owns 64 sorted rows x 64 permuted cols (16 hidden units x all 4 gates).
// A (x-gather / h) and B (weights) stream global->VGPR in MFMA fragment layout;
// all operands are L2/L3-resident. 16 K-chunks, fully unrolled, no __syncthreads.
// c lives in cT[j][n] (f32, transposed) for aligned f32x4 per-lane access.

__global__ __launch_bounds__(256, 4)
void k_step(const ush* __restrict__ embbf, const int* __restrict__ tokperm,
            const int* __restrict__ plens, const int* __restrict__ cnts,
            const ush* __restrict__ wpt_f, const ush* __restrict__ wpt_b,
            const float* __restrict__ bias_f, const float* __restrict__ bias_b,
            const ush* __restrict__ hr_f, ush* __restrict__ hw_f,
            const ush* __restrict__ hr_b, ush* __restrict__ hw_b,
            float* __restrict__ cT_f, float* __restrict__ cT_b,
            int s) {
  const int dir = blockIdx.y;
  const int t = dir ? (15 - s) : s;
  const int cnt = cnts[t];           // prefix incl. graduating generation
  const int wtile = blockIdx.x >> 2;
  const int m0 = wtile * 64;
  if (m0 >= cnt) return;

  const int tid = threadIdx.x;
  const int lane = tid & 63;
  const int w = tid >> 6;
  const int hblk = (blockIdx.x & 3) * 4 + w;  // 0..15
  const int frow = lane & 15;
  const int fkq = lane >> 4;

  const ush* wpt = dir ? wpt_b : wpt_f;
  const float* bias = dir ? bias_b : bias_f;
  const ush* hr = dir ? hr_b : hr_f;
  ush* hw = dir ? hw_b : hw_f;
  float* cT = dir ? cT_b : cT_f;

  // per-row-frag byte offsets (32-bit voffset from SGPR bases)
  unsigned xoff[4], hoff[4], boff[4];
#pragma unroll
  for (int fr = 0; fr < 4; ++fr) {
    const int tokv = tokperm[t * N_SEQ + m0 + fr * 16 + frow];
    xoff[fr] = (unsigned)tokv * (E_DIM * 2) + fkq * 16;
    hoff[fr] = (unsigned)(m0 + fr * 16 + frow) * (H_DIM * 2) + fkq * 16;
  }
#pragma unroll
  for (int q = 0; q < 4; ++q)
    boff[q] = (unsigned)(hblk * 64 + q * 16 + frow) * 1024 + fkq * 16;

  const int j = hblk * 16 + frow;  // hidden unit
  f32x4 acc[4][4];
#pragma unroll
  for (int q = 0; q < 4; ++q) {
    const float bq = bias[q * 256 + j];
#pragma unroll
    for (int fr = 0; fr < 4; ++fr) acc[fr][q] = f32x4{bq, bq, bq, bq};
  }

  const char* xb = (const char*)embbf;
  const char* hb = (const char*)hr;
  const char* bb = (const char*)wpt;

#pragma unroll
  for (int kc = 0; kc < 8; ++kc) {  // x-part, k in [0,256)
    bf16x8 av[4], bv[4];
#pragma unroll
    for (int fr = 0; fr < 4; ++fr) av[fr] = *(const bf16x8*)(xb + xoff[fr] + kc * 64);
#pragma unroll
    for (int q = 0; q < 4; ++q) bv[q] = *(const bf16x8*)(bb + boff[q] + kc * 64);
#pragma unroll
    for (int fr = 0; fr < 4; ++fr)
#pragma unroll
      for (int q = 0; q < 4; ++q)
        acc[fr][q] = __builtin_amdgcn_mfma_f32_16x16x32_bf16(av[fr], bv[q], acc[fr][q], 0, 0, 0);
  }
#pragma unroll
  for (int kc = 0; kc < 8; ++kc) {  // h-part, k in [256,512)
    bf16x8 av[4], bv[4];
#pragma unroll
    for (int fr = 0; fr < 4; ++fr) av[fr] = *(const bf16x8*)(hb + hoff[fr] + kc * 64);
#pragma unroll
    for (int q = 0; q < 4; ++q) bv[q] = *(const bf16x8*)(bb + boff[q] + 512 + kc * 64);
#pragma unroll
    for (int fr = 0; fr < 4; ++fr)
#pragma unroll
      for (int q = 0; q < 4; ++q)
        acc[fr][q] = __builtin_amdgcn_mfma_f32_16x16x32_bf16(av[fr], bv[q], acc[fr][q], 0, 0, 0);
  }

  // ---- fused LSTM cell update: lane holds i,f,g,o for (n = n0+r, hidden j) ----
#pragma unroll
  for (int fr = 0; fr < 4; ++fr) {
    const int n0 = m0 + fr * 16 + fkq * 4;
    const int4 l4 = *(const int4*)&plens[n0];
    f32x4 cv = *(f32x4*)&cT[(size_t)j * N_SEQ + n0];
    const f32x4 gi = acc[fr][0], gf = acc[fr][1], gg = acc[fr][2], go = acc[fr][3];
#pragma unroll
    for (int r = 0; r < 4; ++r) {
      const int lnv = (r == 0) ? l4.x : (r == 1) ? l4.y : (r == 2) ? l4.z : l4.w;
      const size_t hidx = (size_t)(n0 + r) * H_DIM + j;
      if (t < lnv) {
        const float iv = sigmoidf_(gi[r]);
        const float fv = sigmoidf_(gf[r]);
        const float gv = tanhf_(gg[r]);
        const float ov = sigmoidf_(go[r]);
        const float cn = fv * cv[r] + iv * gv;
        cv[r] = cn;
        hw[hidx] = f2bf(ov * tanhf_(cn));
      } else {
        hw[hidx] = hr[hidx];  // buffer-sync copy (graduating / pre-activation rows)
      }
    }
    *(f32x4*)&cT[(size_t)j * N_SEQ + n0] = cv;
  }
}

// ---------------- segment-mean pool (before the linear layer) ----------------

__global__ __launch_bounds__(256) void k_pool(const ush* __restrict__ hf,
                                              const ush* __restrict__ hb,
                                              const int* __restrict__ pinv,
                                              const int* __restrict__ plen,
                                              float* __restrict__ pooled) {
  const int b = blockIdx.x, tid = threadIdx.x;
  int start = 0;
  for (int i = 0; i < b; ++i) start += plen[i];
  const int cnt = plen[b];
  float s0 = 0.f, s1 = 0.f;
  for (int r = 0; r < cnt; ++r) {
    const size_t pr = (size_t)pinv[start + r];
    s0 += bf2f(hf[pr * H_DIM + tid]);
    s1 += bf2f(hb[pr * H_DIM + tid]);
  }
  float inv = 1.0f / (float)cnt;
  pooled[b * 512 + tid] = s0 * inv;
  pooled[b * 512 + H_DIM + tid] = s1 * inv;
}

// ---------------- tiny linear (128x512x512) + L2 normalize, f32 ----------------

__global__ __launch_bounds__(256) void k_final(const float* __restrict__ pooled,
                                               const float* __restrict__ W,
                                               const float* __restrict__ bl,
                                               float* __restrict__ out) {
  const int b = blockIdx.x, tid = threadIdx.x;
  __shared__ float pv[512];
  __shared__ float pre[512];
  __shared__ float red[4];
  pv[tid] = pooled[b * 512 + tid];
  pv[tid + 256] = pooled[b * 512 + 256 + tid];
  __syncthreads();
#pragma unroll
  for (int half = 0; half < 2; ++half) {
    const int dd = tid + half * 256;
    const f32x4* wr = (const f32x4*)(W + (size_t)dd * 512);
    const f32x4* pvv = (const f32x4*)pv;
    float s = bl[dd];
#pragma unroll 4
    for (int k4 = 0; k4 < 128; ++k4) {
      f32x4 wv = wr[k4], xv = pvv[k4];
      s += wv[0] * xv[0] + wv[1] * xv[1] + wv[2] * xv[2] + wv[3] * xv[3];
    }
    pre[dd] = s;
  }
  __syncthreads();
  float ss = pre[tid] * pre[tid] + pre[tid + 256] * pre[tid + 256];
#pragma unroll
  for (int off = 32; off > 0; off >>= 1) ss += __shfl_down(ss, off, 64);
  if ((tid & 63) == 0) red[tid >> 6] = ss;
  __syncthreads();
  float tot = red[0] + red[1] + red[2] + red[3];
  float scale = 1.0f / fmaxf(sqrtf(tot), 1e-5f);
  out[b * 512 + tid] = pre[tid] * scale;
  out[b * 512 + 256 + tid] = pre[tid + 256] * scale;
}

// ---------------- launch ----------------

extern "C" void kernel_launch(void* const* d_in, const int* in_sizes, int n_in,
                              void* d_out, int out_size, void* d_ws, size_t ws_size,
                              hipStream_t stream) {
  const int* tok    = (const int*)d_in[0];
  const int* plen   = (const int*)d_in[1];
  const float* emb  = (const float*)d_in[2];
  const float* Wih_f = (const float*)d_in[3];
  const float* Whh_f = (const float*)d_in[4];
  const float* b_f   = (const float*)d_in[5];
  const float* Wih_b = (const float*)d_in[6];
  const float* Whh_b = (const float*)d_in[7];
  const float* b_b   = (const float*)d_in[8];
  const float* Wlin  = (const float*)d_in[9];
  const float* blin  = (const float*)d_in[10];
  float* out = (float*)d_out;

  char* ws = (char*)d_ws;
  size_t off = 0;
  auto alloc = [&](size_t bytes) {
    void* p = ws + off;
    off = (off + bytes + 255) & ~(size_t)255;
    return p;
  };
  ush* embbf  = (ush*)alloc((size_t)V_SIZE * E_DIM * 2);
  ush* wptf   = (ush*)alloc((size_t)1024 * 512 * 2);
  ush* wptb   = (ush*)alloc((size_t)1024 * 512 * 2);
  int* lens   = (int*)alloc((size_t)N_SEQ * 4);
  int* pinv   = (int*)alloc((size_t)N_SEQ * 4);
  int* plens  = (int*)alloc((size_t)N_SEQ * 4);
  int* tokperm = (int*)alloc((size_t)T_LEN * N_SEQ * 4);
  int* hist   = (int*)alloc(17 * 4);
  int* cursor = (int*)alloc(17 * 4);
  int* cnts   = (int*)alloc(16 * 4);
  ush* h0f    = (ush*)alloc((size_t)N_SEQ * H_DIM * 2);
  ush* h1f    = (ush*)alloc((size_t)N_SEQ * H_DIM * 2);
  ush* h0b    = (ush*)alloc((size_t)N_SEQ * H_DIM * 2);
  ush* h1b    = (ush*)alloc((size_t)N_SEQ * H_DIM * 2);
  float* cTf  = (float*)alloc((size_t)H_DIM * N_SEQ * 4);
  float* cTb  = (float*)alloc((size_t)H_DIM * N_SEQ * 4);
  float* pooled = (float*)alloc((size_t)B_SAMP * 512 * 4);

  hipMemsetAsync(hist, 0, 17 * 4, stream);
  hipMemsetAsync(h0f, 0, (size_t)N_SEQ * H_DIM * 2, stream);
  hipMemsetAsync(h1f, 0, (size_t)N_SEQ * H_DIM * 2, stream);
  hipMemsetAsync(h0b, 0, (size_t)N_SEQ * H_DIM * 2, stream);
  hipMemsetAsync(h1b, 0, (size_t)N_SEQ * H_DIM * 2, stream);
  hipMemsetAsync(cTf, 0, (size_t)H_DIM * N_SEQ * 4, stream);
  hipMemsetAsync(cTb, 0, (size_t)H_DIM * N_SEQ * 4, stream);

  k_lens<<<N_SEQ / 256, 256, 0, stream>>>(tok, lens);
  k_hist<<<N_SEQ / 256, 256, 0, stream>>>(lens, hist);
  k_offsets<<<1, 64, 0, stream>>>(hist, cursor, cnts);
  k_scatter<<<N_SEQ / 256, 256, 0, stream>>>(tok, lens, cursor, pinv, plens, tokperm);
  k_embcvt<<<(V_SIZE * E_DIM) / 256, 256, 0, stream>>>(emb, embbf);
  k_wprep<<<(2 * 1024 * 512) / 256, 256, 0, stream>>>(Wih_f, Whh_f, Wih_b, Whh_b, wptf, wptb);

  dim3 grid(1024, 2);  // 256 row-tiles x 4 hblk-groups, x 2 dirs
  for (int s = 0; s < T_LEN; ++s) {
    const ush* hrf = (s & 1) ? h1f : h0f;
    ush* hwf       = (s & 1) ? h0f : h1f;
    const ush* hrb = (s & 1) ? h1b : h0b;
    ush* hwb       = (s & 1) ? h0b : h1b;
    k_step<<<grid, 256, 0, stream>>>(embbf, tokperm, plens, cnts, wptf, wptb, b_f, b_b,
                                     hrf, hwf, hrb, hwb, cTf, cTb, s);
  }
  // final h for every row lives in h0f / h0b (graduating copies keep buffers synced)
  k_pool<<<B_SAMP, 256, 0, stream>>>(h0f, h0b, pinv, plen, pooled);
  k_final<<<B_SAMP, 256, 0, stream>>>(pooled, Wlin, blin, out);
}

// Round 6
// 923.751 us; speedup vs baseline: 2.1761x; 2.1761x over previous
//
#include <hip/hip_runtime.h>
#include <stdint.h>

#define N_SEQ 16384
#define T_LEN 16
#define E_DIM 256
#define H_DIM 256
#define B_SAMP 128
#define V_SIZE 10000

typedef __bf16 bf16x8 __attribute__((ext_vector_type(8)));
typedef float  f32x4  __attribute__((ext_vector_type(4)));
typedef unsigned short u16x8 __attribute__((ext_vector_type(8)));
typedef unsigned short ush;

__device__ __forceinline__ ush f2bf(float x) {
  unsigned int u = __float_as_uint(x);
  u = (u + 0x7fffu + ((u >> 16) & 1u)) >> 16;
  return (ush)u;
}
__device__ __forceinline__ float bf2f(ush v) {
  return __uint_as_float(((unsigned int)v) << 16);
}
__device__ __forceinline__ float sigmoidf_(float x) {
  return 1.0f / (1.0f + __expf(-x));
}
__device__ __forceinline__ float tanhf_(float x) {
  float e = __expf(2.0f * x);
  return 1.0f - 2.0f / (e + 1.0f);
}
__device__ __forceinline__ void glds16(const void* g, const void* l) {
  __builtin_amdgcn_global_load_lds(
      (const __attribute__((address_space(1))) unsigned int*)g,
      (__attribute__((address_space(3))) unsigned int*)l, 16, 0, 0);
}

// ---------------- prep kernels ----------------

__global__ __launch_bounds__(256) void k_lens(const int* __restrict__ tok, int* __restrict__ lens) {
  int n = blockIdx.x * 256 + threadIdx.x;
  const int* r = tok + n * T_LEN;
  int c = 0;
#pragma unroll
  for (int t = 0; t < T_LEN; ++t) c += (r[t] != 0);
  lens[n] = c;
}

__global__ __launch_bounds__(256) void k_hist(const int* __restrict__ lens, int* __restrict__ hist) {
  __shared__ int lh[17];
  if (threadIdx.x < 17) lh[threadIdx.x] = 0;
  __syncthreads();
  atomicAdd(&lh[lens[blockIdx.x * 256 + threadIdx.x]], 1);
  __syncthreads();
  if (threadIdx.x < 17) atomicAdd(&hist[threadIdx.x], lh[threadIdx.x]);
}

// descending-length bucket starts; cnts_f[t]=count(len>=t) (incl. graduating copy),
// cnts_b[t]=count(len>t) (bwd needs no copies: pre-activation h is 0 in both buffers)
__global__ void k_offsets(const int* __restrict__ hist, int* __restrict__ cursor,
                          int* __restrict__ cnts_f, int* __restrict__ cnts_b) {
  if (threadIdx.x == 0) {
    int off = 0;
    for (int l = 16; l >= 0; --l) { cursor[l] = off; off += hist[l]; }
    for (int t = 0; t < 16; ++t) {
      int cf = 0, cb = 0;
      for (int l = t; l <= 16; ++l) cf += hist[l];
      for (int l = t + 1; l <= 16; ++l) cb += hist[l];
      cnts_f[t] = cf;
      cnts_b[t] = cb;
    }
  }
}

__global__ __launch_bounds__(256) void k_scatter(const int* __restrict__ tok, const int* __restrict__ lens,
                                                 int* __restrict__ cursor,
                                                 int* __restrict__ pinv, int* __restrict__ plens,
                                                 int* __restrict__ tokperm) {
  int n = blockIdx.x * 256 + threadIdx.x;
  int l = lens[n];
  int pos = atomicAdd(&cursor[l], 1);
  pinv[n] = pos;
  plens[pos] = l;
#pragma unroll
  for (int t = 0; t < T_LEN; ++t) tokperm[t * N_SEQ + pos] = tok[n * T_LEN + t];
}

__global__ __launch_bounds__(256) void k_embcvt(const float* __restrict__ emb, ush* __restrict__ out) {
  int i = blockIdx.x * 256 + threadIdx.x;
  out[i] = f2bf(emb[i]);
}

// Permuted weights, pcol p <-> (j = (p>>6)*16 + (p&15), gate q = (p>>4)&3), gate-row r = q*256+j.
// mat 0: Wih -> wihp[dir][p][k] (k<256); mat 1: Whh -> whhp[dir][p][k].
__global__ __launch_bounds__(256) void k_wprep(const float* __restrict__ Wih_f, const float* __restrict__ Whh_f,
                                               const float* __restrict__ Wih_b, const float* __restrict__ Whh_b,
                                               ush* __restrict__ wihp_f, ush* __restrict__ wihp_b,
                                               ush* __restrict__ whhp_f, ush* __restrict__ whhp_b) {
  int id = blockIdx.x * 256 + threadIdx.x;  // < 2*2*1024*256
  int mat = id >> 19;
  int dir = (id >> 18) & 1;
  int rem = id & ((1 << 18) - 1);
  int p = rem >> 8;
  int k = rem & 255;
  int r = ((p >> 4) & 3) * 256 + (p >> 6) * 16 + (p & 15);
  const float* src = mat ? (dir ? Whh_b : Whh_f) : (dir ? Wih_b : Wih_f);
  ush* dst = mat ? (dir ? whhp_b : whhp_f) : (dir ? wihp_b : wihp_f);
  dst[p * 256 + k] = f2bf(src[r * 256 + k]);
}

// ---------------- vocab projection: projX[v][pcol] = (emb @ Wih_perm^T)[v][pcol], f32 ----------------
// Tile 128 rows x 256 pcols, K=256 (4 chunks of 64), 512 threads / 8 waves of 64x64.

__global__ __launch_bounds__(512, 4)
void k_vproj(const ush* __restrict__ embbf,
             const ush* __restrict__ wihp_f, const ush* __restrict__ wihp_b,
             float* __restrict__ proj_f, float* __restrict__ proj_b) {
  const int dir = blockIdx.y;
  const int wtile = blockIdx.x >> 2;
  const int nblk = blockIdx.x & 3;
  const int m0 = wtile * 128;
  const ush* wih = dir ? wihp_b : wihp_f;
  float* proj = dir ? proj_b : proj_f;

  __shared__ __align__(128) unsigned char ldsA[128 * 128];
  __shared__ __align__(128) unsigned char ldsB[256 * 128];

  const int tid = threadIdx.x;
  const int lane = tid & 63;
  const int w = tid >> 6;
  const int wr = w >> 2, wc = w & 3;
  const int l8 = lane >> 3, l7 = lane & 7;
  const int frow = lane & 15, fkq = lane >> 4;

  const int arow0 = 16 * w + l8, arow1 = arow0 + 8;
  const unsigned aoff0 = (unsigned)(m0 + arow0) * 256 + (l7 ^ (arow0 & 7)) * 8;
  const unsigned aoff1 = (unsigned)(m0 + arow1) * 256 + (l7 ^ (arow1 & 7)) * 8;
  unsigned boff[4];
#pragma unroll
  for (int j = 0; j < 4; ++j) {
    const int brow = 32 * w + 8 * j + l8;
    boff[j] = (unsigned)(nblk * 256 + brow) * 256 + (l7 ^ (brow & 7)) * 8;
  }

  f32x4 acc[4][4] = {};
  for (int kt = 0; kt < 4; ++kt) {
    const int k0 = kt * 64;
    glds16(embbf + aoff0 + k0, &ldsA[(16 * w) * 128]);
    glds16(embbf + aoff1 + k0, &ldsA[(16 * w + 8) * 128]);
#pragma unroll
    for (int j = 0; j < 4; ++j)
      glds16(wih + boff[j] + k0, &ldsB[(32 * w + 8 * j) * 128]);
    __syncthreads();
#pragma unroll
    for (int ksub = 0; ksub < 2; ++ksub) {
      bf16x8 av[4], bv[4];
#pragma unroll
      for (int fr = 0; fr < 4; ++fr) {
        const int row = wr * 64 + fr * 16 + frow;
        av[fr] = *(const bf16x8*)&ldsA[row * 128 + (((ksub * 4 + fkq) ^ (row & 7)) * 16)];
      }
#pragma unroll
      for (int fc = 0; fc < 4; ++fc) {
        const int row = wc * 64 + fc * 16 + frow;
        bv[fc] = *(const bf16x8*)&ldsB[row * 128 + (((ksub * 4 + fkq) ^ (row & 7)) * 16)];
      }
#pragma unroll
      for (int fr = 0; fr < 4; ++fr)
#pragma unroll
        for (int fc = 0; fc < 4; ++fc)
          acc[fr][fc] = __builtin_amdgcn_mfma_f32_16x16x32_bf16(av[fr], bv[fc], acc[fr][fc], 0, 0, 0);
    }
    __syncthreads();
  }

  const int pcb = nblk * 256 + wc * 64 + frow;
#pragma unroll
  for (int fr = 0; fr < 4; ++fr) {
    const int v0 = m0 + wr * 64 + fr * 16 + fkq * 4;
#pragma unroll
    for (int q = 0; q < 4; ++q)
#pragma unroll
      for (int r = 0; r < 4; ++r)
        if (v0 + r < V_SIZE) proj[(size_t)(v0 + r) * 1024 + pcb + q * 16] = acc[fr][q][r];
  }
}

// ---------------- LSTM step: K=256 recurrent GEMM + projX epilogue + cell update ----------------

__global__ __launch_bounds__(512, 4)
void k_step(const float* __restrict__ proj_f, const float* __restrict__ proj_b,
            const int* __restrict__ tokperm, const int* __restrict__ plens,
            const int* __restrict__ cnts_f, const int* __restrict__ cnts_b,
            const ush* __restrict__ whhp_f, const ush* __restrict__ whhp_b,
            const float* __restrict__ bias_f, const float* __restrict__ bias_b,
            const ush* __restrict__ hr_f, ush* __restrict__ hw_f,
            const ush* __restrict__ hr_b, ush* __restrict__ hw_b,
            float* __restrict__ cT_f, float* __restrict__ cT_b,
            int s) {
  const int dir = blockIdx.y;
  const int t = dir ? (15 - s) : s;
  const int cnt = dir ? cnts_b[t] : cnts_f[t];
  const int wtile = blockIdx.x >> 2;
  const int m0 = wtile * 128;
  if (m0 >= cnt) return;

  const int nblk = blockIdx.x & 3;
  const float* proj = dir ? proj_b : proj_f;
  const ush* whh = dir ? whhp_b : whhp_f;
  const float* bias = dir ? bias_b : bias_f;
  const ush* hr = dir ? hr_b : hr_f;
  ush* hw = dir ? hw_b : hw_f;
  float* cT = dir ? cT_b : cT_f;

  __shared__ __align__(128) unsigned char ldsA[128 * 128];
  __shared__ __align__(128) unsigned char ldsB[256 * 128];

  const int tid = threadIdx.x;
  const int lane = tid & 63;
  const int w = tid >> 6;
  const int wr = w >> 2, wc = w & 3;
  const int l8 = lane >> 3, l7 = lane & 7;
  const int frow = lane & 15, fkq = lane >> 4;

  const int arow0 = 16 * w + l8, arow1 = arow0 + 8;
  const unsigned aoff0 = (unsigned)(m0 + arow0) * 256 + (l7 ^ (arow0 & 7)) * 8;
  const unsigned aoff1 = (unsigned)(m0 + arow1) * 256 + (l7 ^ (arow1 & 7)) * 8;
  unsigned boff[4];
#pragma unroll
  for (int j = 0; j < 4; ++j) {
    const int brow = 32 * w + 8 * j + l8;
    boff[j] = (unsigned)(nblk * 256 + brow) * 256 + (l7 ^ (brow & 7)) * 8;
  }

  f32x4 acc[4][4] = {};
  for (int kt = 0; kt < 4; ++kt) {
    const int k0 = kt * 64;
    glds16(hr + aoff0 + k0, &ldsA[(16 * w) * 128]);
    glds16(hr + aoff1 + k0, &ldsA[(16 * w + 8) * 128]);
#pragma unroll
    for (int j = 0; j < 4; ++j)
      glds16(whh + boff[j] + k0, &ldsB[(32 * w + 8 * j) * 128]);
    __syncthreads();
#pragma unroll
    for (int ksub = 0; ksub < 2; ++ksub) {
      bf16x8 av[4], bv[4];
#pragma unroll
      for (int fr = 0; fr < 4; ++fr) {
        const int row = wr * 64 + fr * 16 + frow;
        av[fr] = *(const bf16x8*)&ldsA[row * 128 + (((ksub * 4 + fkq) ^ (row & 7)) * 16)];
      }
#pragma unroll
      for (int fc = 0; fc < 4; ++fc) {
        const int row = wc * 64 + fc * 16 + frow;
        bv[fc] = *(const bf16x8*)&ldsB[row * 128 + (((ksub * 4 + fkq) ^ (row & 7)) * 16)];
      }
#pragma unroll
      for (int fr = 0; fr < 4; ++fr)
#pragma unroll
        for (int fc = 0; fc < 4; ++fc)
          acc[fr][fc] = __builtin_amdgcn_mfma_f32_16x16x32_bf16(av[fr], bv[fc], acc[fr][fc], 0, 0, 0);
    }
    __syncthreads();
  }

  // ---- epilogue: gates = acc + bias + projX[tok], then cell update ----
  const int j = nblk * 64 + wc * 16 + frow;
  const int pcb = nblk * 256 + wc * 64 + frow;  // + q*16
  const float b0 = bias[j], b1 = bias[256 + j], b2 = bias[512 + j], b3 = bias[768 + j];
#pragma unroll
  for (int fr = 0; fr < 4; ++fr) {
    const int n0 = m0 + wr * 64 + fr * 16 + fkq * 4;
    const int4 l4 = *(const int4*)&plens[n0];
    const int4 tv = *(const int4*)&tokperm[t * N_SEQ + n0];
    f32x4 cv = *(f32x4*)&cT[(size_t)j * N_SEQ + n0];
    f32x4 gi = acc[fr][0], gf = acc[fr][1], gg = acc[fr][2], go = acc[fr][3];
#pragma unroll
    for (int r = 0; r < 4; ++r) {
      const int tvr = (r == 0) ? tv.x : (r == 1) ? tv.y : (r == 2) ? tv.z : tv.w;
      const float* pr = proj + (size_t)tvr * 1024 + pcb;
      gi[r] += b0 + pr[0];
      gf[r] += b1 + pr[16];
      gg[r] += b2 + pr[32];
      go[r] += b3 + pr[48];
    }
#pragma unroll
    for (int r = 0; r < 4; ++r) {
      const int lnv = (r == 0) ? l4.x : (r == 1) ? l4.y : (r == 2) ? l4.z : l4.w;
      const size_t hidx = (size_t)(n0 + r) * H_DIM + j;
      if (t < lnv) {
        const float iv = sigmoidf_(gi[r]);
        const float fv = sigmoidf_(gf[r]);
        const float gv = tanhf_(gg[r]);
        const float ov = sigmoidf_(go[r]);
        const float cn = fv * cv[r] + iv * gv;
        cv[r] = cn;
        hw[hidx] = f2bf(ov * tanhf_(cn));
      } else {
        hw[hidx] = hr[hidx];  // fwd graduation copy; idempotent afterwards
      }
    }
    *(f32x4*)&cT[(size_t)j * N_SEQ + n0] = cv;
  }
}

// ---------------- segment-mean pool (before the linear layer) ----------------

__global__ __launch_bounds__(256) void k_pool(const ush* __restrict__ hf,
                                              const ush* __restrict__ hb,
                                              const int* __restrict__ pinv,
                                              const int* __restrict__ plen,
                                              float* __restrict__ pooled) {
  const int b = blockIdx.x, tid = threadIdx.x;
  int start = 0;
  for (int i = 0; i < b; ++i) start += plen[i];
  const int cnt = plen[b];
  float s0 = 0.f, s1 = 0.f;
  for (int r = 0; r < cnt; ++r) {
    const size_t pr = (size_t)pinv[start + r];
    s0 += bf2f(hf[pr * H_DIM + tid]);
    s1 += bf2f(hb[pr * H_DIM + tid]);
  }
  float inv = 1.0f / (float)cnt;
  pooled[b * 512 + tid] = s0 * inv;
  pooled[b * 512 + H_DIM + tid] = s1 * inv;
}

// ---------------- tiny linear (128x512x512) + L2 normalize, f32 ----------------

__global__ __launch_bounds__(256) void k_final(const float* __restrict__ pooled,
                                               const float* __restrict__ W,
                                               const float* __restrict__ bl,
                                               float* __restrict__ out) {
  const int b = blockIdx.x, tid = threadIdx.x;
  __shared__ float pv[512];
  __shared__ float pre[512];
  __shared__ float red[4];
  pv[tid] = pooled[b * 512 + tid];
  pv[tid + 256] = pooled[b * 512 + 256 + tid];
  __syncthreads();
#pragma unroll
  for (int half = 0; half < 2; ++half) {
    const int dd = tid + half * 256;
    const f32x4* wr = (const f32x4*)(W + (size_t)dd * 512);
    const f32x4* pvv = (const f32x4*)pv;
    float s = bl[dd];
#pragma unroll 4
    for (int k4 = 0; k4 < 128; ++k4) {
      f32x4 wv = wr[k4], xv = pvv[k4];
      s += wv[0] * xv[0] + wv[1] * xv[1] + wv[2] * xv[2] + wv[3] * xv[3];
    }
    pre[dd] = s;
  }
  __syncthreads();
  float ss = pre[tid] * pre[tid] + pre[tid + 256] * pre[tid + 256];
#pragma unroll
  for (int off = 32; off > 0; off >>= 1) ss += __shfl_down(ss, off, 64);
  if ((tid & 63) == 0) red[tid >> 6] = ss;
  __syncthreads();
  float tot = red[0] + red[1] + red[2] + red[3];
  float scale = 1.0f / fmaxf(sqrtf(tot), 1e-5f);
  out[b * 512 + tid] = pre[tid] * scale;
  out[b * 512 + 256 + tid] = pre[tid + 256] * scale;
}

// ---------------- launch ----------------

extern "C" void kernel_launch(void* const* d_in, const int* in_sizes, int n_in,
                              void* d_out, int out_size, void* d_ws, size_t ws_size,
                              hipStream_t stream) {
  const int* tok    = (const int*)d_in[0];
  const int* plen   = (const int*)d_in[1];
  const float* emb  = (const float*)d_in[2];
  const float* Wih_f = (const float*)d_in[3];
  const float* Whh_f = (const float*)d_in[4];
  const float* b_f   = (const float*)d_in[5];
  const float* Wih_b = (const float*)d_in[6];
  const float* Whh_b = (const float*)d_in[7];
  const float* b_b   = (const float*)d_in[8];
  const float* Wlin  = (const float*)d_in[9];
  const float* blin  = (const float*)d_in[10];
  float* out = (float*)d_out;

  char* ws = (char*)d_ws;
  size_t off = 0;
  auto alloc = [&](size_t bytes) {
    void* p = ws + off;
    off = (off + bytes + 255) & ~(size_t)255;
    return p;
  };
  ush* embbf   = (ush*)alloc((size_t)V_SIZE * E_DIM * 2);
  ush* wihpf   = (ush*)alloc((size_t)1024 * 256 * 2);
  ush* wihpb   = (ush*)alloc((size_t)1024 * 256 * 2);
  ush* whhpf   = (ush*)alloc((size_t)1024 * 256 * 2);
  ush* whhpb   = (ush*)alloc((size_t)1024 * 256 * 2);
  int* lens    = (int*)alloc((size_t)N_SEQ * 4);
  int* pinv    = (int*)alloc((size_t)N_SEQ * 4);
  int* plens   = (int*)alloc((size_t)N_SEQ * 4);
  int* tokperm = (int*)alloc((size_t)T_LEN * N_SEQ * 4);
  int* hist    = (int*)alloc(17 * 4);
  int* cursor  = (int*)alloc(17 * 4);
  int* cntsf   = (int*)alloc(16 * 4);
  int* cntsb   = (int*)alloc(16 * 4);
  float* projf = (float*)alloc((size_t)V_SIZE * 1024 * 4);
  float* projb = (float*)alloc((size_t)V_SIZE * 1024 * 4);
  ush* h0f     = (ush*)alloc((size_t)N_SEQ * H_DIM * 2);
  ush* h1f     = (ush*)alloc((size_t)N_SEQ * H_DIM * 2);
  ush* h0b     = (ush*)alloc((size_t)N_SEQ * H_DIM * 2);
  ush* h1b     = (ush*)alloc((size_t)N_SEQ * H_DIM * 2);
  float* cTf   = (float*)alloc((size_t)H_DIM * N_SEQ * 4);
  float* cTb   = (float*)alloc((size_t)H_DIM * N_SEQ * 4);
  float* pooled = (float*)alloc((size_t)B_SAMP * 512 * 4);

  hipMemsetAsync(hist, 0, 17 * 4, stream);
  hipMemsetAsync(h0f, 0, (size_t)N_SEQ * H_DIM * 2, stream);
  hipMemsetAsync(h1f, 0, (size_t)N_SEQ * H_DIM * 2, stream);
  hipMemsetAsync(h0b, 0, (size_t)N_SEQ * H_DIM * 2, stream);
  hipMemsetAsync(h1b, 0, (size_t)N_SEQ * H_DIM * 2, stream);
  hipMemsetAsync(cTf, 0, (size_t)H_DIM * N_SEQ * 4, stream);
  hipMemsetAsync(cTb, 0, (size_t)H_DIM * N_SEQ * 4, stream);

  k_lens<<<N_SEQ / 256, 256, 0, stream>>>(tok, lens);
  k_hist<<<N_SEQ / 256, 256, 0, stream>>>(lens, hist);
  k_offsets<<<1, 64, 0, stream>>>(hist, cursor, cntsf, cntsb);
  k_scatter<<<N_SEQ / 256, 256, 0, stream>>>(tok, lens, cursor, pinv, plens, tokperm);
  k_embcvt<<<(V_SIZE * E_DIM) / 256, 256, 0, stream>>>(emb, embbf);
  k_wprep<<<(2 * 2 * 1024 * 256) / 256, 256, 0, stream>>>(Wih_f, Whh_f, Wih_b, Whh_b,
                                                           wihpf, wihpb, whhpf, whhpb);
  k_vproj<<<dim3(79 * 4, 2), 512, 0, stream>>>(embbf, wihpf, wihpb, projf, projb);

  dim3 grid(512, 2);  // 128 row-tiles x 4 col-blocks, x 2 dirs
  for (int s = 0; s < T_LEN; ++s) {
    const ush* hrf = (s & 1) ? h1f : h0f;
    ush* hwf       = (s & 1) ? h0f : h1f;
    const ush* hrb = (s & 1) ? h1b : h0b;
    ush* hwb       = (s & 1) ? h0b : h1b;
    k_step<<<grid, 512, 0, stream>>>(projf, projb, tokperm, plens, cntsf, cntsb,
                                     whhpf, whhpb, b_f, b_b,
                                     hrf, hwf, hrb, hwb, cTf, cTb, s);
  }
  // final h in h0f / h0b (fwd graduation copies keep buffers synced; bwd all-active at s=15)
  k_pool<<<B_SAMP, 256, 0, stream>>>(h0f, h0b, pinv, plen, pooled);
  k_final<<<B_SAMP, 256, 0, stream>>>(pooled, Wlin, blin, out);
}